// Round 1
// baseline (392.419 us; speedup 1.0000x reference)
//
#include <hip/hip_runtime.h>
#include <hip/hip_bf16.h>

using bf16 = __hip_bfloat16;
typedef __attribute__((ext_vector_type(8))) short short8;   // 8 x bf16 MFMA operand
typedef __attribute__((ext_vector_type(4))) float floatx4;  // MFMA accumulator

#define AS1 __attribute__((address_space(1)))
#define AS3 __attribute__((address_space(3)))

__device__ __forceinline__ floatx4 mfma16(short8 a, short8 b, floatx4 c) {
  return __builtin_amdgcn_mfma_f32_16x16x32_bf16(a, b, c, 0, 0, 0);
}
// async global->LDS, 16B per lane; LDS dest = wave-uniform base + lane*16
__device__ __forceinline__ void gload16(const bf16* g, bf16* l) {
  __builtin_amdgcn_global_load_lds((const AS1 unsigned*)g, (AS3 unsigned*)l, 16, 0, 0);
}

// ---------------- cast fp32 -> bf16 (4 elems/thread) ----------------
__global__ void cast_bf16_k(const float* __restrict__ src, bf16* __restrict__ dst, int n) {
  int i = (blockIdx.x * 256 + threadIdx.x) * 4;
  if (i >= n) return;
  float4 v = *(const float4*)(src + i);
  bf16 t[4] = {__float2bfloat16(v.x), __float2bfloat16(v.y),
               __float2bfloat16(v.z), __float2bfloat16(v.w)};
  *(ushort4*)(dst + i) = *(const ushort4*)t;
}

// ------- GEMM C[M,N] = A[M,K] * B[N,K]^T, bf16 in, OutT out -------
// 128x128 tile, BK=32, 256 thr (4 waves in 2x2), global_load_lds staging,
// XOR-swizzled LDS (pos = g ^ ((row>>1)&3)) -> 2-way (free) bank aliasing.
template <typename OutT>
__global__ __launch_bounds__(256, 2)
void gemm_bt(const bf16* __restrict__ A, const bf16* __restrict__ B,
             OutT* __restrict__ C, int M, int N, int K) {
  __shared__ alignas(16) bf16 As[128 * 32];
  __shared__ alignas(16) bf16 Bs[128 * 32];
  const int tid = threadIdx.x;
  const int w = tid >> 6, lane = tid & 63, l16 = lane & 15, quad = lane >> 4;
  const int bm = blockIdx.x << 7, bn = blockIdx.y << 7;
  const int wm = (w & 1) << 6, wn = (w >> 1) << 6;

  const int r = tid >> 2, p = tid & 3;
  const int g0 = (p ^ ((r >> 1) & 3)) << 3;            // source group (elems)
  const int g1 = (p ^ (((r + 64) >> 1) & 3)) << 3;
  const bf16* Ag0 = A + (long)(bm + r) * K + g0;
  const bf16* Ag1 = A + (long)(bm + r + 64) * K + g1;
  const bf16* Bg0 = B + (long)(bn + r) * K + g0;
  const bf16* Bg1 = B + (long)(bn + r + 64) * K + g1;
  bf16* Asw = As + (w << 9);  // wave LDS base (64 lanes * 8 elems)
  bf16* Bsw = Bs + (w << 9);

  floatx4 acc[4][4];
#pragma unroll
  for (int i = 0; i < 4; ++i)
#pragma unroll
    for (int j = 0; j < 4; ++j) acc[i][j] = (floatx4)(0.0f);

  for (int k0 = 0; k0 < K; k0 += 32) {
    gload16(Ag0 + k0, Asw);
    gload16(Ag1 + k0, Asw + 2048);
    gload16(Bg0 + k0, Bsw);
    gload16(Bg1 + k0, Bsw + 2048);
    __syncthreads();
    short8 af[4], bfv[4];
#pragma unroll
    for (int mi = 0; mi < 4; ++mi) {
      int row = wm + (mi << 4) + l16;
      int pos = quad ^ ((row >> 1) & 3);
      af[mi] = *(const short8*)(As + row * 32 + pos * 8);
    }
#pragma unroll
    for (int ni = 0; ni < 4; ++ni) {
      int row = wn + (ni << 4) + l16;
      int pos = quad ^ ((row >> 1) & 3);
      bfv[ni] = *(const short8*)(Bs + row * 32 + pos * 8);
    }
#pragma unroll
    for (int mi = 0; mi < 4; ++mi)
#pragma unroll
      for (int ni = 0; ni < 4; ++ni)
        acc[mi][ni] = mfma16(af[mi], bfv[ni], acc[mi][ni]);
    __syncthreads();
  }

#pragma unroll
  for (int mi = 0; mi < 4; ++mi)
#pragma unroll
    for (int ni = 0; ni < 4; ++ni)
#pragma unroll
      for (int rr = 0; rr < 4; ++rr) {
        int row = bm + wm + (mi << 4) + (quad << 2) + rr;  // C/D: row=quad*4+reg
        int col = bn + wn + (ni << 4) + l16;               //      col=lane&15
        float v = acc[mi][ni][rr];
        if constexpr (sizeof(OutT) == 2)
          C[(long)row * N + col] = __float2bfloat16(v);
        else
          C[(long)row * N + col] = v;
      }
}

// ---------------- RoPE: qkv[4096][3072] -> Q[B,H,S,DH]*scale, K[B,KVH,S,DH] ----
__global__ void rope_k(const bf16* __restrict__ qkv, bf16* __restrict__ Q,
                       bf16* __restrict__ Kd) {
  int idx = blockIdx.x * 256 + threadIdx.x;  // 4096*20*64 threads, d-pair each
  int d = idx & 63;
  int rest = idx >> 6;
  int head = rest % 20;
  int token = rest / 20;
  int s = token & 2047;
  int b = token >> 11;
  const float C0 = 0.20762050593046439f;  // log2(10000)/64
  float i1 = (float)(d >> 1);
  float inv1 = exp2f(-i1 * C0);
  float inv2 = exp2f(-(i1 + 32.0f) * C0);
  float a1 = (float)s * inv1, a2 = (float)s * inv2;
  float s1, c1, s2, c2;
  sincosf(a1, &s1, &c1);
  sincosf(a2, &s2, &c2);
  if (head < 16) {
    const bf16* p = qkv + (long)token * 3072 + head * 128 + d;
    float xlo = __bfloat162float(p[0]), xhi = __bfloat162float(p[64]);
    const float sc = 0.08838834764831845f;  // 1/sqrt(128) folded into Q
    float olo = (xlo * c1 - xhi * s1) * sc;
    float ohi = (xhi * c2 + xlo * s2) * sc;
    bf16* q = Q + ((long)((b << 4) + head) * 2048 + s) * 128 + d;
    q[0] = __float2bfloat16(olo);
    q[64] = __float2bfloat16(ohi);
  } else {
    int kvh = head - 16;
    const bf16* p = qkv + (long)token * 3072 + 2048 + kvh * 128 + d;
    float xlo = __bfloat162float(p[0]), xhi = __bfloat162float(p[64]);
    float olo = xlo * c1 - xhi * s1;
    float ohi = xhi * c2 + xlo * s2;
    bf16* kk = Kd + ((long)((b << 2) + kvh) * 2048 + s) * 128 + d;
    kk[0] = __float2bfloat16(olo);
    kk[64] = __float2bfloat16(ohi);
  }
}

// ---------------- V transpose: qkv V cols -> Vt[B,KVH,DH,S] ----------------
__global__ void vtrans_k(const bf16* __restrict__ qkv, bf16* __restrict__ Vt) {
  __shared__ bf16 t[32][33];
  int x = threadIdx.x, y = threadIdx.y;
  int s0 = blockIdx.x << 5, d0 = blockIdx.y << 5, bkv = blockIdx.z;
  int b = bkv >> 2, kvh = bkv & 3;
  const bf16* src = qkv + (long)((b << 11) + s0) * 3072 + 2560 + kvh * 128 + d0;
#pragma unroll
  for (int yy = y; yy < 32; yy += 8) t[yy][x] = src[(long)yy * 3072 + x];
  __syncthreads();
  bf16* dst = Vt + (long)((bkv << 7) + d0) * 2048 + s0;
#pragma unroll
  for (int yy = y; yy < 32; yy += 8) dst[(long)yy * 2048 + x] = t[x][yy];
}

// ---------------- flash attention, BQ=64 (4 waves x 16 rows), BKV=64 --------
// mask: key k valid iff k <= q + 128 (past fully visible + 128 lookahead)
__global__ __launch_bounds__(256, 2)
void attn_k(const bf16* __restrict__ Q, const bf16* __restrict__ K,
            const bf16* __restrict__ V, bf16* __restrict__ O) {
  __shared__ alignas(16) bf16 lk[64 * 128];  // [key][d]   16KB
  __shared__ alignas(16) bf16 lv[128 * 64];  // [d][key]   16KB
  __shared__ alignas(16) bf16 lp[4 * 16 * 64];  // P per wave  8KB
  const int tid = threadIdx.x, w = tid >> 6, lane = tid & 63;
  const int l16 = lane & 15, quad = lane >> 4;
  const int q0 = blockIdx.x << 6;
  const int bh = blockIdx.y, b = bh >> 4, h = bh & 15, kvh = h >> 2;
  const bf16* Qp = Q + ((long)bh * 2048 + q0 + (w << 4)) * 128;
  const bf16* Kp = K + (long)((b << 2) + kvh) * 2048 * 128;
  const bf16* Vp = V + (long)((b << 2) + kvh) * 128 * 2048;

  short8 qf[4];  // Q A-frags: lane m=l16, k=quad*8.., kc over DH/32
#pragma unroll
  for (int kc = 0; kc < 4; ++kc)
    qf[kc] = *(const short8*)(Qp + (long)l16 * 128 + kc * 32 + quad * 8);

  floatx4 oacc[8];
#pragma unroll
  for (int i = 0; i < 8; ++i) oacc[i] = (floatx4)(0.0f);
  float m_i[4], l_i[4];
#pragma unroll
  for (int rr = 0; rr < 4; ++rr) { m_i[rr] = -1e30f; l_i[rr] = 0.0f; }

  const int sp = (l16 ^ (l16 >> 3)) & 7;  // lp read swizzle (row = l16)
  bf16* pw = lp + (w << 10);

  int jl = (q0 + 191) >> 6;
  const int jlast = jl < 31 ? jl : 31;
  for (int j = 0; j <= jlast; ++j) {
    const int k0 = j << 6;
    // stage K tile [64][128]: chunk c -> row c>>4, pos c&15; src grp swizzled
#pragma unroll
    for (int i = 0; i < 4; ++i) {
      int c = i * 256 + tid;
      int row = c >> 4, pos = c & 15;
      int grp = (pos & 8) | ((pos & 7) ^ (row & 7));
      gload16(Kp + (long)(k0 + row) * 128 + grp * 8, lk + (i * 256 + (w << 6)) * 8);
    }
    // stage V tile [128][64]: chunk c -> row c>>3, pos c&7
#pragma unroll
    for (int i = 0; i < 4; ++i) {
      int c = i * 256 + tid;
      int row = c >> 3, grp = (c & 7) ^ (row & 7);
      gload16(Vp + (long)row * 2048 + k0 + grp * 8, lv + (i * 256 + (w << 6)) * 8);
    }
    __syncthreads();

    floatx4 sacc[4];
#pragma unroll
    for (int ni = 0; ni < 4; ++ni) sacc[ni] = (floatx4)(0.0f);
#pragma unroll
    for (int kc = 0; kc < 4; ++kc) {
#pragma unroll
      for (int ni = 0; ni < 4; ++ni) {
        int row = (ni << 4) + l16;
        int g = (kc << 2) + quad;
        int pos = (g & 8) | ((g & 7) ^ (row & 7));
        short8 kf = *(const short8*)(lk + row * 128 + pos * 8);
        sacc[ni] = mfma16(qf[kc], kf, sacc[ni]);
      }
    }

    if (k0 + 63 > q0 + 128) {  // only the straddling tile needs masking
#pragma unroll
      for (int ni = 0; ni < 4; ++ni) {
        int kg = k0 + (ni << 4) + l16;
#pragma unroll
        for (int rr = 0; rr < 4; ++rr) {
          int qg = q0 + (w << 4) + (quad << 2) + rr;
          if (kg > qg + 128) sacc[ni][rr] = -1e30f;
        }
      }
    }

    // online softmax (rows live in quad-lanes; reduce across 16 lanes)
    float rmax[4], rsum[4];
#pragma unroll
    for (int rr = 0; rr < 4; ++rr) {
      float v = fmaxf(fmaxf(sacc[0][rr], sacc[1][rr]), fmaxf(sacc[2][rr], sacc[3][rr]));
      rmax[rr] = v;
    }
#pragma unroll
    for (int off = 1; off <= 8; off <<= 1)
#pragma unroll
      for (int rr = 0; rr < 4; ++rr)
        rmax[rr] = fmaxf(rmax[rr], __shfl_xor(rmax[rr], off, 64));
    float al[4];
#pragma unroll
    for (int rr = 0; rr < 4; ++rr) {
      float mn = fmaxf(m_i[rr], rmax[rr]);
      al[rr] = __expf(m_i[rr] - mn);
      m_i[rr] = mn;
      rsum[rr] = 0.0f;
    }
#pragma unroll
    for (int ni = 0; ni < 4; ++ni)
#pragma unroll
      for (int rr = 0; rr < 4; ++rr) {
        float pv = __expf(sacc[ni][rr] - m_i[rr]);
        sacc[ni][rr] = pv;
        rsum[rr] += pv;
      }
#pragma unroll
    for (int off = 1; off <= 8; off <<= 1)
#pragma unroll
      for (int rr = 0; rr < 4; ++rr) rsum[rr] += __shfl_xor(rsum[rr], off, 64);
#pragma unroll
    for (int rr = 0; rr < 4; ++rr) l_i[rr] = l_i[rr] * al[rr] + rsum[rr];
#pragma unroll
    for (int ni = 0; ni < 8; ++ni)
#pragma unroll
      for (int rr = 0; rr < 4; ++rr) oacc[ni][rr] *= al[rr];

    // P (C-layout) -> per-wave LDS in A-layout order, swizzle (r^(r>>3))&7
#pragma unroll
    for (int ni = 0; ni < 4; ++ni) {
      int cc = (ni << 4) + l16;
      int g = cc >> 3;
#pragma unroll
      for (int rr = 0; rr < 4; ++rr) {
        int row = (quad << 2) + rr;
        int srow = (row ^ (row >> 3)) & 7;
        pw[row * 64 + ((g ^ srow) << 3) + (cc & 7)] = __float2bfloat16(sacc[ni][rr]);
      }
    }

    // PV: oacc[d-tiles] += P * V
#pragma unroll
    for (int kc = 0; kc < 2; ++kc) {
      int g = (kc << 2) + quad;
      short8 pf = *(const short8*)(pw + l16 * 64 + ((g ^ sp) << 3));
#pragma unroll
      for (int ni = 0; ni < 8; ++ni) {
        int vrow = (ni << 4) + l16;
        int vpos = g ^ (vrow & 7);
        short8 vf = *(const short8*)(lv + vrow * 64 + (vpos << 3));
        oacc[ni] = mfma16(pf, vf, oacc[ni]);
      }
    }
    __syncthreads();
  }

  float rl[4];
#pragma unroll
  for (int rr = 0; rr < 4; ++rr) rl[rr] = 1.0f / l_i[rr];
  bf16* Op = O + ((long)(b << 11) + q0 + (w << 4)) * 2048 + (h << 7);
#pragma unroll
  for (int ni = 0; ni < 8; ++ni)
#pragma unroll
    for (int rr = 0; rr < 4; ++rr) {
      int row = (quad << 2) + rr;
      int col = (ni << 4) + l16;
      Op[(long)row * 2048 + col] = __float2bfloat16(oacc[ni][rr] * rl[rr]);
    }
}

extern "C" void kernel_launch(void* const* d_in, const int* in_sizes, int n_in,
                              void* d_out, int out_size, void* d_ws, size_t ws_size,
                              hipStream_t stream) {
  (void)in_sizes; (void)n_in; (void)out_size; (void)ws_size;
  const float* x  = (const float*)d_in[0];
  const float* Wq = (const float*)d_in[1];
  const float* Wk = (const float*)d_in[2];
  const float* Wv = (const float*)d_in[3];
  const float* Wo = (const float*)d_in[4];
  char* ws = (char*)d_ws;
  // ws layout (bytes): xb 16.7M | wqkv 12.6M | wo_b 8.4M | qkv 25.2M | Q 16.8M | K 4.2M | Vt 4.2M
  bf16* xb   = (bf16*)(ws);                 // also reused as Ob after gemm1
  bf16* wqkv = (bf16*)(ws + 16777216);
  bf16* wo_b = (bf16*)(ws + 29360128);
  bf16* qkv  = (bf16*)(ws + 37748736);
  bf16* Qr   = (bf16*)(ws + 62914560);
  bf16* Kr   = (bf16*)(ws + 79691776);
  bf16* Vt   = (bf16*)(ws + 83886080);
  bf16* Ob   = xb;  // x dead after QKV GEMM
  float* out = (float*)d_out;

  cast_bf16_k<<<8192, 256, 0, stream>>>(x, xb, 8388608);
  cast_bf16_k<<<4096, 256, 0, stream>>>(Wq, wqkv, 4194304);
  cast_bf16_k<<<1024, 256, 0, stream>>>(Wk, wqkv + 2048 * 2048, 1048576);
  cast_bf16_k<<<1024, 256, 0, stream>>>(Wv, wqkv + 2560 * 2048, 1048576);
  cast_bf16_k<<<4096, 256, 0, stream>>>(Wo, wo_b, 4194304);

  gemm_bt<bf16><<<dim3(32, 24), 256, 0, stream>>>(xb, wqkv, qkv, 4096, 3072, 2048);
  rope_k<<<20480, 256, 0, stream>>>(qkv, Qr, Kr);
  vtrans_k<<<dim3(64, 4, 8), dim3(32, 8), 0, stream>>>(qkv, Vt);
  attn_k<<<dim3(32, 32), 256, 0, stream>>>(Qr, Kr, Vt, Ob);
  gemm_bt<float><<<dim3(32, 16), 256, 0, stream>>>(Ob, wo_b, out, 4096, 2048, 2048);
}

// Round 3
// 335.727 us; speedup vs baseline: 1.1689x; 1.1689x over previous
//
#include <hip/hip_runtime.h>
#include <hip/hip_bf16.h>

using bf16 = __hip_bfloat16;
typedef __attribute__((ext_vector_type(8))) short short8;   // 8 x bf16 MFMA operand
typedef __attribute__((ext_vector_type(4))) float floatx4;  // MFMA accumulator

#define AS1 __attribute__((address_space(1)))
#define AS3 __attribute__((address_space(3)))

__device__ __forceinline__ floatx4 mfma16(short8 a, short8 b, floatx4 c) {
  return __builtin_amdgcn_mfma_f32_16x16x32_bf16(a, b, c, 0, 0, 0);
}
// async global->LDS, 16B per lane; LDS dest = wave-uniform base + lane*16
__device__ __forceinline__ void gload16(const bf16* g, bf16* l) {
  __builtin_amdgcn_global_load_lds((const AS1 unsigned*)g, (AS3 unsigned*)l, 16, 0, 0);
}

// ---------------- cast fp32 -> bf16 (4 elems/thread) ----------------
__global__ void cast_bf16_k(const float* __restrict__ src, bf16* __restrict__ dst, int n) {
  int i = (blockIdx.x * 256 + threadIdx.x) * 4;
  if (i >= n) return;
  float4 v = *(const float4*)(src + i);
  bf16 t[4] = {__float2bfloat16(v.x), __float2bfloat16(v.y),
               __float2bfloat16(v.z), __float2bfloat16(v.w)};
  *(ushort4*)(dst + i) = *(const ushort4*)t;
}

// ------- GEMM C[M,N] = A[M,K] * B[N,K]^T, bf16 in, OutT out -------
template <typename OutT>
__global__ __launch_bounds__(256, 2)
void gemm_bt(const bf16* __restrict__ A, const bf16* __restrict__ B,
             OutT* __restrict__ C, int M, int N, int K) {
  __shared__ alignas(16) bf16 As[128 * 32];
  __shared__ alignas(16) bf16 Bs[128 * 32];
  const int tid = threadIdx.x;
  const int w = tid >> 6, lane = tid & 63, l16 = lane & 15, quad = lane >> 4;
  const int bm = blockIdx.x << 7, bn = blockIdx.y << 7;
  const int wm = (w & 1) << 6, wn = (w >> 1) << 6;

  const int r = tid >> 2, p = tid & 3;
  const int g0 = (p ^ ((r >> 1) & 3)) << 3;            // source group (elems)
  const int g1 = (p ^ (((r + 64) >> 1) & 3)) << 3;
  const bf16* Ag0 = A + (long)(bm + r) * K + g0;
  const bf16* Ag1 = A + (long)(bm + r + 64) * K + g1;
  const bf16* Bg0 = B + (long)(bn + r) * K + g0;
  const bf16* Bg1 = B + (long)(bn + r + 64) * K + g1;
  bf16* Asw = As + (w << 9);  // wave LDS base (64 lanes * 8 elems)
  bf16* Bsw = Bs + (w << 9);

  floatx4 acc[4][4];
#pragma unroll
  for (int i = 0; i < 4; ++i)
#pragma unroll
    for (int j = 0; j < 4; ++j) acc[i][j] = (floatx4)(0.0f);

  for (int k0 = 0; k0 < K; k0 += 32) {
    gload16(Ag0 + k0, Asw);
    gload16(Ag1 + k0, Asw + 2048);
    gload16(Bg0 + k0, Bsw);
    gload16(Bg1 + k0, Bsw + 2048);
    __syncthreads();
    short8 af[4], bfv[4];
#pragma unroll
    for (int mi = 0; mi < 4; ++mi) {
      int row = wm + (mi << 4) + l16;
      int pos = quad ^ ((row >> 1) & 3);
      af[mi] = *(const short8*)(As + row * 32 + pos * 8);
    }
#pragma unroll
    for (int ni = 0; ni < 4; ++ni) {
      int row = wn + (ni << 4) + l16;
      int pos = quad ^ ((row >> 1) & 3);
      bfv[ni] = *(const short8*)(Bs + row * 32 + pos * 8);
    }
#pragma unroll
    for (int mi = 0; mi < 4; ++mi)
#pragma unroll
      for (int ni = 0; ni < 4; ++ni)
        acc[mi][ni] = mfma16(af[mi], bfv[ni], acc[mi][ni]);
    __syncthreads();
  }

#pragma unroll
  for (int mi = 0; mi < 4; ++mi)
#pragma unroll
    for (int ni = 0; ni < 4; ++ni)
#pragma unroll
      for (int rr = 0; rr < 4; ++rr) {
        int row = bm + wm + (mi << 4) + (quad << 2) + rr;  // C/D: row=quad*4+reg
        int col = bn + wn + (ni << 4) + l16;               //      col=lane&15
        float v = acc[mi][ni][rr];
        if constexpr (sizeof(OutT) == 2)
          C[(long)row * N + col] = __float2bfloat16(v);
        else
          C[(long)row * N + col] = v;
      }
}

// ---------------- RoPE: qkv[4096][3072] -> Q[B,H,S,DH]*scale, K[B,KVH,S,DH] ----
// Q scale = 1/sqrt(128) * log2(e): attention exp(s) becomes exp2(s') directly.
__global__ void rope_k(const bf16* __restrict__ qkv, bf16* __restrict__ Q,
                       bf16* __restrict__ Kd) {
  int idx = blockIdx.x * 256 + threadIdx.x;  // 4096*20*64 threads, d-pair each
  int d = idx & 63;
  int rest = idx >> 6;
  int head = rest % 20;
  int token = rest / 20;
  int s = token & 2047;
  int b = token >> 11;
  const float C0 = 0.20762050593046439f;  // log2(10000)/64
  float i1 = (float)(d >> 1);
  float inv1 = exp2f(-i1 * C0);
  float inv2 = exp2f(-(i1 + 32.0f) * C0);
  float a1 = (float)s * inv1, a2 = (float)s * inv2;
  float s1, c1, s2, c2;
  sincosf(a1, &s1, &c1);
  sincosf(a2, &s2, &c2);
  if (head < 16) {
    const bf16* p = qkv + (long)token * 3072 + head * 128 + d;
    float xlo = __bfloat162float(p[0]), xhi = __bfloat162float(p[64]);
    const float sc = 0.08838834764831845f * 1.4426950408889634f;  // 1/sqrt(128)*log2e
    float olo = (xlo * c1 - xhi * s1) * sc;
    float ohi = (xhi * c2 + xlo * s2) * sc;
    bf16* q = Q + ((long)((b << 4) + head) * 2048 + s) * 128 + d;
    q[0] = __float2bfloat16(olo);
    q[64] = __float2bfloat16(ohi);
  } else {
    int kvh = head - 16;
    const bf16* p = qkv + (long)token * 3072 + 2048 + kvh * 128 + d;
    float xlo = __bfloat162float(p[0]), xhi = __bfloat162float(p[64]);
    float olo = xlo * c1 - xhi * s1;
    float ohi = xhi * c2 + xlo * s2;
    bf16* kk = Kd + ((long)((b << 2) + kvh) * 2048 + s) * 128 + d;
    kk[0] = __float2bfloat16(olo);
    kk[64] = __float2bfloat16(ohi);
  }
}

// ---------------- V transpose: qkv V cols -> Vt[B,KVH,DH,S] ----------------
__global__ void vtrans_k(const bf16* __restrict__ qkv, bf16* __restrict__ Vt) {
  __shared__ bf16 t[32][33];
  int x = threadIdx.x, y = threadIdx.y;
  int s0 = blockIdx.x << 5, d0 = blockIdx.y << 5, bkv = blockIdx.z;
  int b = bkv >> 2, kvh = bkv & 3;
  const bf16* src = qkv + (long)((b << 11) + s0) * 3072 + 2560 + kvh * 128 + d0;
#pragma unroll
  for (int yy = y; yy < 32; yy += 8) t[yy][x] = src[(long)yy * 3072 + x];
  __syncthreads();
  bf16* dst = Vt + (long)((bkv << 7) + d0) * 2048 + s0;
#pragma unroll
  for (int yy = y; yy < 32; yy += 8) dst[(long)yy * 2048 + x] = t[x][yy];
}

// ---------------- flash attention, paired q-tiles, no-max exp2 softmax ------
// mask: key k valid iff k <= q + 128. Block bx handles q-tiles bx (A, light)
// and 31-bx (B, heavy). Key tile j straddles A's window at j == bx+2 and
// B's window at j == 33-bx (the latter only exists when bx >= 2).
// Scores arrive pre-scaled by log2e/sqrt(128) -> P = exp2(s), no max-sub
// (|s'| <~ 8 hard-bounded, fp32 sums safe), no rescale, l reduced once at end.
__global__ __launch_bounds__(256, 2)
void attn_k(const bf16* __restrict__ Q, const bf16* __restrict__ K,
            const bf16* __restrict__ V, bf16* __restrict__ O) {
  __shared__ alignas(16) bf16 lk[64 * 128];     // [key][d]   16KB
  __shared__ alignas(16) bf16 lv[128 * 64];     // [d][key]   16KB
  __shared__ alignas(16) bf16 lpA[4 * 16 * 64]; // P per wave  8KB
  __shared__ alignas(16) bf16 lpB[4 * 16 * 64]; // P per wave  8KB
  const int tid = threadIdx.x, w = tid >> 6, lane = tid & 63;
  const int l16 = lane & 15, quad = lane >> 4;
  const int bx = blockIdx.x;
  const int qa0 = bx << 6, qb0 = (31 - bx) << 6;
  const int ja_last = bx + 2;                 // qa straddle tile
  const int jb_mask = 33 - bx;                // qb straddle tile (>31 if bx<2)
  const int jb_last = jb_mask < 31 ? jb_mask : 31;
  const int bh = blockIdx.y, b = bh >> 4, h = bh & 15, kvh = h >> 2;
  const bf16* Qp = Q + (long)bh * 2048 * 128;
  const bf16* Kp = K + (long)((b << 2) + kvh) * 2048 * 128;
  const bf16* Vp = V + (long)((b << 2) + kvh) * 128 * 2048;

  short8 qfA[4], qfB[4];  // A-frags: m=l16, k=quad*8.., kc over DH/32
#pragma unroll
  for (int kc = 0; kc < 4; ++kc) {
    qfA[kc] = *(const short8*)(Qp + (long)(qa0 + (w << 4) + l16) * 128 + kc * 32 + quad * 8);
    qfB[kc] = *(const short8*)(Qp + (long)(qb0 + (w << 4) + l16) * 128 + kc * 32 + quad * 8);
  }

  floatx4 oA[8], oB[8];
#pragma unroll
  for (int i = 0; i < 8; ++i) { oA[i] = (floatx4)(0.0f); oB[i] = (floatx4)(0.0f); }
  float lAcc[4], lBcc[4];
#pragma unroll
  for (int rr = 0; rr < 4; ++rr) { lAcc[rr] = 0.0f; lBcc[rr] = 0.0f; }

  const int sp = (l16 ^ (l16 >> 3)) & 7;  // P read swizzle (row = l16)
  bf16* pwA = lpA + (w << 10);
  bf16* pwB = lpB + (w << 10);

  auto tile = [&](auto bothc, int k0, bool maskA, bool maskB) {
    constexpr bool BOTH = decltype(bothc)::value;
    floatx4 sA[4], sB[4];
#pragma unroll
    for (int ni = 0; ni < 4; ++ni) {
      sB[ni] = (floatx4)(0.0f);
      if constexpr (BOTH) sA[ni] = (floatx4)(0.0f);
    }
    // QK^T: shared kf feeds both accumulator sets
#pragma unroll
    for (int kc = 0; kc < 4; ++kc) {
#pragma unroll
      for (int ni = 0; ni < 4; ++ni) {
        int row = (ni << 4) + l16;
        int g = (kc << 2) + quad;
        int pos = (g & 8) | ((g & 7) ^ (row & 7));
        short8 kf = *(const short8*)(lk + row * 128 + pos * 8);
        sB[ni] = mfma16(qfB[kc], kf, sB[ni]);
        if constexpr (BOTH) sA[ni] = mfma16(qfA[kc], kf, sA[ni]);
      }
    }
    if constexpr (BOTH) {
      if (maskA) {
#pragma unroll
        for (int ni = 0; ni < 4; ++ni) {
          int kg = k0 + (ni << 4) + l16;
#pragma unroll
          for (int rr = 0; rr < 4; ++rr) {
            int qg = qa0 + (w << 4) + (quad << 2) + rr;
            if (kg > qg + 128) sA[ni][rr] = -1e30f;
          }
        }
      }
    }
    if (maskB) {
#pragma unroll
      for (int ni = 0; ni < 4; ++ni) {
        int kg = k0 + (ni << 4) + l16;
#pragma unroll
        for (int rr = 0; rr < 4; ++rr) {
          int qg = qb0 + (w << 4) + (quad << 2) + rr;
          if (kg > qg + 128) sB[ni][rr] = -1e30f;
        }
      }
    }
    // P = exp2(s); accumulate row-partial l; write P (bf16) to per-wave LDS
#pragma unroll
    for (int ni = 0; ni < 4; ++ni) {
      int cc = (ni << 4) + l16;
      int g = cc >> 3;
#pragma unroll
      for (int rr = 0; rr < 4; ++rr) {
        int row = (quad << 2) + rr;
        int srow = (row ^ (row >> 3)) & 7;
        int addr = row * 64 + ((g ^ srow) << 3) + (cc & 7);
        float pB = exp2f(sB[ni][rr]);
        lBcc[rr] += pB;
        pwB[addr] = __float2bfloat16(pB);
        if constexpr (BOTH) {
          float pA = exp2f(sA[ni][rr]);
          lAcc[rr] += pA;
          pwA[addr] = __float2bfloat16(pA);
        }
      }
    }
    // PV: shared vf feeds both
#pragma unroll
    for (int kc = 0; kc < 2; ++kc) {
      int g = (kc << 2) + quad;
      short8 pfB = *(const short8*)(pwB + l16 * 64 + ((g ^ sp) << 3));
      short8 pfA;
      if constexpr (BOTH) pfA = *(const short8*)(pwA + l16 * 64 + ((g ^ sp) << 3));
#pragma unroll
      for (int ni = 0; ni < 8; ++ni) {
        int vrow = (ni << 4) + l16;
        int vpos = g ^ (vrow & 7);
        short8 vf = *(const short8*)(lv + vrow * 64 + (vpos << 3));
        oB[ni] = mfma16(pfB, vf, oB[ni]);
        if constexpr (BOTH) oA[ni] = mfma16(pfA, vf, oA[ni]);
      }
    }
  };

  for (int j = 0; j <= jb_last; ++j) {
    const int k0 = j << 6;
    // stage K tile [64][128]: chunk c -> row c>>4, pos c&15; src grp swizzled
#pragma unroll
    for (int i = 0; i < 4; ++i) {
      int c = i * 256 + tid;
      int row = c >> 4, pos = c & 15;
      int grp = (pos & 8) | ((pos & 7) ^ (row & 7));
      gload16(Kp + (long)(k0 + row) * 128 + grp * 8, lk + (i * 256 + (w << 6)) * 8);
    }
    // stage V tile [128][64]: chunk c -> row c>>3, pos c&7
#pragma unroll
    for (int i = 0; i < 4; ++i) {
      int c = i * 256 + tid;
      int row = c >> 3, grp = (c & 7) ^ (row & 7);
      gload16(Vp + (long)row * 2048 + k0 + grp * 8, lv + (i * 256 + (w << 6)) * 8);
    }
    __syncthreads();
    if (j <= ja_last)
      tile(std::integral_constant<bool, true>{}, k0, j == ja_last, j == jb_mask);
    else
      tile(std::integral_constant<bool, false>{}, k0, false, j == jb_mask);
    __syncthreads();
  }

  // reduce l across the 16 lanes sharing a row-quad, then normalize + store
#pragma unroll
  for (int off = 1; off <= 8; off <<= 1)
#pragma unroll
    for (int rr = 0; rr < 4; ++rr) {
      lAcc[rr] += __shfl_xor(lAcc[rr], off, 64);
      lBcc[rr] += __shfl_xor(lBcc[rr], off, 64);
    }
  float rlA[4], rlB[4];
#pragma unroll
  for (int rr = 0; rr < 4; ++rr) { rlA[rr] = 1.0f / lAcc[rr]; rlB[rr] = 1.0f / lBcc[rr]; }

  bf16* OpA = O + ((long)(b << 11) + qa0 + (w << 4)) * 2048 + (h << 7);
  bf16* OpB = O + ((long)(b << 11) + qb0 + (w << 4)) * 2048 + (h << 7);
#pragma unroll
  for (int ni = 0; ni < 8; ++ni)
#pragma unroll
    for (int rr = 0; rr < 4; ++rr) {
      int row = (quad << 2) + rr;
      int col = (ni << 4) + l16;
      OpA[(long)row * 2048 + col] = __float2bfloat16(oA[ni][rr] * rlA[rr]);
      OpB[(long)row * 2048 + col] = __float2bfloat16(oB[ni][rr] * rlB[rr]);
    }
}

extern "C" void kernel_launch(void* const* d_in, const int* in_sizes, int n_in,
                              void* d_out, int out_size, void* d_ws, size_t ws_size,
                              hipStream_t stream) {
  (void)in_sizes; (void)n_in; (void)out_size; (void)ws_size;
  const float* x  = (const float*)d_in[0];
  const float* Wq = (const float*)d_in[1];
  const float* Wk = (const float*)d_in[2];
  const float* Wv = (const float*)d_in[3];
  const float* Wo = (const float*)d_in[4];
  char* ws = (char*)d_ws;
  // ws layout (bytes): xb 16.7M | wqkv 12.6M | wo_b 8.4M | qkv 25.2M | Q 16.8M | K 4.2M | Vt 4.2M
  bf16* xb   = (bf16*)(ws);                 // also reused as Ob after gemm1
  bf16* wqkv = (bf16*)(ws + 16777216);
  bf16* wo_b = (bf16*)(ws + 29360128);
  bf16* qkv  = (bf16*)(ws + 37748736);
  bf16* Qr   = (bf16*)(ws + 62914560);
  bf16* Kr   = (bf16*)(ws + 79691776);
  bf16* Vt   = (bf16*)(ws + 83886080);
  bf16* Ob   = xb;  // x dead after QKV GEMM
  float* out = (float*)d_out;

  cast_bf16_k<<<8192, 256, 0, stream>>>(x, xb, 8388608);
  cast_bf16_k<<<4096, 256, 0, stream>>>(Wq, wqkv, 4194304);
  cast_bf16_k<<<1024, 256, 0, stream>>>(Wk, wqkv + 2048 * 2048, 1048576);
  cast_bf16_k<<<1024, 256, 0, stream>>>(Wv, wqkv + 2560 * 2048, 1048576);
  cast_bf16_k<<<4096, 256, 0, stream>>>(Wo, wo_b, 4194304);

  gemm_bt<bf16><<<dim3(32, 24), 256, 0, stream>>>(xb, wqkv, qkv, 4096, 3072, 2048);
  rope_k<<<20480, 256, 0, stream>>>(qkv, Qr, Kr);
  vtrans_k<<<dim3(64, 4, 8), dim3(32, 8), 0, stream>>>(qkv, Vt);
  attn_k<<<dim3(16, 32), 256, 0, stream>>>(Qr, Kr, Vt, Ob);
  gemm_bt<float><<<dim3(32, 16), 256, 0, stream>>>(Ob, wo_b, out, 4096, 2048, 2048);
}

// Round 4
// 311.263 us; speedup vs baseline: 1.2607x; 1.0786x over previous
//
#include <hip/hip_runtime.h>
#include <hip/hip_bf16.h>

using bf16 = __hip_bfloat16;
typedef __attribute__((ext_vector_type(8))) short short8;   // 8 x bf16 MFMA operand
typedef __attribute__((ext_vector_type(4))) float floatx4;  // MFMA accumulator

#define AS1 __attribute__((address_space(1)))
#define AS3 __attribute__((address_space(3)))

__device__ __forceinline__ floatx4 mfma16(short8 a, short8 b, floatx4 c) {
  return __builtin_amdgcn_mfma_f32_16x16x32_bf16(a, b, c, 0, 0, 0);
}
// async global->LDS, 16B per lane; LDS dest = wave-uniform base + lane*16
__device__ __forceinline__ void gload16(const bf16* g, bf16* l) {
  __builtin_amdgcn_global_load_lds((const AS1 unsigned*)g, (AS3 unsigned*)l, 16, 0, 0);
}

// ------------- fused fp32 -> bf16 casts for all 5 inputs (one launch) -------
__global__ void cast_all_k(const float* __restrict__ x, const float* __restrict__ Wq,
                           const float* __restrict__ Wk, const float* __restrict__ Wv,
                           const float* __restrict__ Wo, bf16* __restrict__ xb,
                           bf16* __restrict__ wqkv, bf16* __restrict__ wo_b) {
  int blk = blockIdx.x;
  const float* src;
  bf16* dst;
  int off;
  if (blk < 8192)       { src = x;  dst = xb;                 off = blk; }
  else if (blk < 12288) { src = Wq; dst = wqkv;               off = blk - 8192; }
  else if (blk < 13312) { src = Wk; dst = wqkv + 2048 * 2048; off = blk - 12288; }
  else if (blk < 14336) { src = Wv; dst = wqkv + 2560 * 2048; off = blk - 13312; }
  else                  { src = Wo; dst = wo_b;               off = blk - 14336; }
  int i = (off * 256 + threadIdx.x) * 4;
  float4 v = *(const float4*)(src + i);
  bf16 t[4] = {__float2bfloat16(v.x), __float2bfloat16(v.y),
               __float2bfloat16(v.z), __float2bfloat16(v.w)};
  *(ushort4*)(dst + i) = *(const ushort4*)t;
}

// ------- GEMM C[M,N] = A[M,K] * B[N,K]^T, bf16 in, OutT out -------
template <typename OutT>
__global__ __launch_bounds__(256, 2)
void gemm_bt(const bf16* __restrict__ A, const bf16* __restrict__ B,
             OutT* __restrict__ C, int M, int N, int K) {
  __shared__ alignas(16) bf16 As[128 * 32];
  __shared__ alignas(16) bf16 Bs[128 * 32];
  const int tid = threadIdx.x;
  const int w = tid >> 6, lane = tid & 63, l16 = lane & 15, quad = lane >> 4;
  const int bm = blockIdx.x << 7, bn = blockIdx.y << 7;
  const int wm = (w & 1) << 6, wn = (w >> 1) << 6;

  const int r = tid >> 2, p = tid & 3;
  const int g0 = (p ^ ((r >> 1) & 3)) << 3;            // source group (elems)
  const int g1 = (p ^ (((r + 64) >> 1) & 3)) << 3;
  const bf16* Ag0 = A + (long)(bm + r) * K + g0;
  const bf16* Ag1 = A + (long)(bm + r + 64) * K + g1;
  const bf16* Bg0 = B + (long)(bn + r) * K + g0;
  const bf16* Bg1 = B + (long)(bn + r + 64) * K + g1;
  bf16* Asw = As + (w << 9);  // wave LDS base (64 lanes * 8 elems)
  bf16* Bsw = Bs + (w << 9);

  floatx4 acc[4][4];
#pragma unroll
  for (int i = 0; i < 4; ++i)
#pragma unroll
    for (int j = 0; j < 4; ++j) acc[i][j] = (floatx4)(0.0f);

  for (int k0 = 0; k0 < K; k0 += 32) {
    gload16(Ag0 + k0, Asw);
    gload16(Ag1 + k0, Asw + 2048);
    gload16(Bg0 + k0, Bsw);
    gload16(Bg1 + k0, Bsw + 2048);
    __syncthreads();
    short8 af[4], bfv[4];
#pragma unroll
    for (int mi = 0; mi < 4; ++mi) {
      int row = wm + (mi << 4) + l16;
      int pos = quad ^ ((row >> 1) & 3);
      af[mi] = *(const short8*)(As + row * 32 + pos * 8);
    }
#pragma unroll
    for (int ni = 0; ni < 4; ++ni) {
      int row = wn + (ni << 4) + l16;
      int pos = quad ^ ((row >> 1) & 3);
      bfv[ni] = *(const short8*)(Bs + row * 32 + pos * 8);
    }
#pragma unroll
    for (int mi = 0; mi < 4; ++mi)
#pragma unroll
      for (int ni = 0; ni < 4; ++ni)
        acc[mi][ni] = mfma16(af[mi], bfv[ni], acc[mi][ni]);
    __syncthreads();
  }

#pragma unroll
  for (int mi = 0; mi < 4; ++mi)
#pragma unroll
    for (int ni = 0; ni < 4; ++ni)
#pragma unroll
      for (int rr = 0; rr < 4; ++rr) {
        int row = bm + wm + (mi << 4) + (quad << 2) + rr;  // C/D: row=quad*4+reg
        int col = bn + wn + (ni << 4) + l16;               //      col=lane&15
        float v = acc[mi][ni][rr];
        if constexpr (sizeof(OutT) == 2)
          C[(long)row * N + col] = __float2bfloat16(v);
        else
          C[(long)row * N + col] = v;
      }
}

// ---------------- RoPE: qkv[4096][3072] -> Q[B,H,S,DH]*scale, K[B,KVH,S,DH] ----
// Q scale = 1/sqrt(128) * log2(e): attention exp(s) becomes exp2(s') directly.
__global__ void rope_k(const bf16* __restrict__ qkv, bf16* __restrict__ Q,
                       bf16* __restrict__ Kd) {
  int idx = blockIdx.x * 256 + threadIdx.x;  // 4096*20*64 threads, d-pair each
  int d = idx & 63;
  int rest = idx >> 6;
  int head = rest % 20;
  int token = rest / 20;
  int s = token & 2047;
  int b = token >> 11;
  const float C0 = 0.20762050593046439f;  // log2(10000)/64
  float i1 = (float)(d >> 1);
  float inv1 = exp2f(-i1 * C0);
  float inv2 = exp2f(-(i1 + 32.0f) * C0);
  float a1 = (float)s * inv1, a2 = (float)s * inv2;
  float s1, c1, s2, c2;
  sincosf(a1, &s1, &c1);
  sincosf(a2, &s2, &c2);
  if (head < 16) {
    const bf16* p = qkv + (long)token * 3072 + head * 128 + d;
    float xlo = __bfloat162float(p[0]), xhi = __bfloat162float(p[64]);
    const float sc = 0.08838834764831845f * 1.4426950408889634f;  // 1/sqrt(128)*log2e
    float olo = (xlo * c1 - xhi * s1) * sc;
    float ohi = (xhi * c2 + xlo * s2) * sc;
    bf16* q = Q + ((long)((b << 4) + head) * 2048 + s) * 128 + d;
    q[0] = __float2bfloat16(olo);
    q[64] = __float2bfloat16(ohi);
  } else {
    int kvh = head - 16;
    const bf16* p = qkv + (long)token * 3072 + 2048 + kvh * 128 + d;
    float xlo = __bfloat162float(p[0]), xhi = __bfloat162float(p[64]);
    float olo = xlo * c1 - xhi * s1;
    float ohi = xhi * c2 + xlo * s2;
    bf16* kk = Kd + ((long)((b << 2) + kvh) * 2048 + s) * 128 + d;
    kk[0] = __float2bfloat16(olo);
    kk[64] = __float2bfloat16(ohi);
  }
}

// ---------------- V transpose: qkv V cols -> Vt[B,KVH,DH,S] ----------------
__global__ void vtrans_k(const bf16* __restrict__ qkv, bf16* __restrict__ Vt) {
  __shared__ bf16 t[32][33];
  int x = threadIdx.x, y = threadIdx.y;
  int s0 = blockIdx.x << 5, d0 = blockIdx.y << 5, bkv = blockIdx.z;
  int b = bkv >> 2, kvh = bkv & 3;
  const bf16* src = qkv + (long)((b << 11) + s0) * 3072 + 2560 + kvh * 128 + d0;
#pragma unroll
  for (int yy = y; yy < 32; yy += 8) t[yy][x] = src[(long)yy * 3072 + x];
  __syncthreads();
  bf16* dst = Vt + (long)((bkv << 7) + d0) * 2048 + s0;
#pragma unroll
  for (int yy = y; yy < 32; yy += 8) dst[(long)yy * 2048 + x] = t[x][yy];
}

// -------- flash attention: paired q-tiles, BKV=128, S^T + packed P-store ----
// mask: key k valid iff k <= q + 128. Block bx: q-tiles A=bx (light), B=31-bx
// (heavy). 128-key tiles: nk(t) = min(t/2+2, 16); straddle tile jm(t)=t/2+1
// (when <= nk-1). QK^T computed transposed (A=K, B=Q) so per-lane P values are
// 4 consecutive keys of one query (col=l16) -> single ds_write_b64 per 16-key
// tile; l is one scalar/lane, reduced across quads once at the end.
__global__ __launch_bounds__(256, 2)
void attn_k(const bf16* __restrict__ Q, const bf16* __restrict__ K,
            const bf16* __restrict__ V, bf16* __restrict__ O) {
  __shared__ alignas(16) bf16 lk[128 * 128];    // [key][d]   32KB
  __shared__ alignas(16) bf16 lv[128 * 128];    // [d][key]   32KB
  __shared__ alignas(16) bf16 lpA[4 * 16 * 64]; // P half-tile per wave  8KB
  __shared__ alignas(16) bf16 lpB[4 * 16 * 64]; // P half-tile per wave  8KB
  const int tid = threadIdx.x, w = tid >> 6, lane = tid & 63;
  const int l16 = lane & 15, quad = lane >> 4;
  const int bx = blockIdx.x;
  const int qa0 = bx << 6, qb0 = (31 - bx) << 6;
  const int nkA = (bx >> 1) + 2;                       // <= 9, no clip needed
  int nkBt = ((31 - bx) >> 1) + 2;
  const int nkB = nkBt < 16 ? nkBt : 16;               // clip at S/128
  const int jmA = (bx >> 1) + 1, jmB = ((31 - bx) >> 1) + 1;
  const int bh = blockIdx.y, b = bh >> 4, h = bh & 15, kvh = h >> 2;
  const bf16* Qp = Q + (long)bh * 2048 * 128;
  const bf16* Kp = K + (long)((b << 2) + kvh) * 2048 * 128;
  const bf16* Vp = V + (long)((b << 2) + kvh) * 128 * 2048;

  short8 qfA[4], qfB[4];  // Q B-frags: n=l16(query), k=quad*8.., kc over DH/32
#pragma unroll
  for (int kc = 0; kc < 4; ++kc) {
    qfA[kc] = *(const short8*)(Qp + (long)(qa0 + (w << 4) + l16) * 128 + kc * 32 + quad * 8);
    qfB[kc] = *(const short8*)(Qp + (long)(qb0 + (w << 4) + l16) * 128 + kc * 32 + quad * 8);
  }

  floatx4 oA[8], oB[8];
#pragma unroll
  for (int i = 0; i < 8; ++i) { oA[i] = (floatx4)(0.0f); oB[i] = (floatx4)(0.0f); }
  float lA = 0.0f, lB = 0.0f;   // per-lane l for query l16 (summed over quads later)

  bf16* pwA = lpA + (w << 10);  // 16 q x 64 k per wave
  bf16* pwB = lpB + (w << 10);
  const int sw = l16 & 7;       // P pair-swizzle

  auto tile = [&](auto bothc, int k0, bool maskA, bool maskB) {
    constexpr bool BOTH = decltype(bothc)::value;
    floatx4 sA[8], sB[8];
#pragma unroll
    for (int kt = 0; kt < 8; ++kt) {
      sB[kt] = (floatx4)(0.0f);
      if constexpr (BOTH) sA[kt] = (floatx4)(0.0f);
    }
    // S^T = K*Q^T: shared kf (A-operand, m=key) feeds both query tiles
#pragma unroll
    for (int kc = 0; kc < 4; ++kc) {
#pragma unroll
      for (int kt = 0; kt < 8; ++kt) {
        int row = (kt << 4) + l16;
        int g = (kc << 2) + quad;
        int pos = (g & 8) | ((g & 7) ^ (row & 7));
        short8 kf = *(const short8*)(lk + row * 128 + pos * 8);
        sB[kt] = mfma16(kf, qfB[kc], sB[kt]);
        if constexpr (BOTH) sA[kt] = mfma16(kf, qfA[kc], sA[kt]);
      }
    }
    // mask: S^T value (kt,rr): key = k0+kt*16+quad*4+rr, query = qX0+w*16+l16
    if (maskB) {
      int qg = qb0 + (w << 4) + l16 + 128;
#pragma unroll
      for (int kt = 0; kt < 8; ++kt)
#pragma unroll
        for (int rr = 0; rr < 4; ++rr) {
          int kg = k0 + (kt << 4) + (quad << 2) + rr;
          if (kg > qg) sB[kt][rr] = -1e30f;
        }
    }
    if constexpr (BOTH) {
      if (maskA) {
        int qg = qa0 + (w << 4) + l16 + 128;
#pragma unroll
        for (int kt = 0; kt < 8; ++kt)
#pragma unroll
          for (int rr = 0; rr < 4; ++rr) {
            int kg = k0 + (kt << 4) + (quad << 2) + rr;
            if (kg > qg) sA[kt][rr] = -1e30f;
          }
      }
    }
    // two 64-key halves: exp2 + packed b64 P-store, then PV
#pragma unroll
    for (int hh = 0; hh < 2; ++hh) {
#pragma unroll
      for (int t = 0; t < 4; ++t) {
        int kt = (hh << 2) + t;
        int slot = (t << 2) + quad;
        int sl = ((((slot >> 1) ^ sw) << 1) | (quad & 1)) << 2;  // elem offset
        {
          float p0 = exp2f(sB[kt][0]), p1 = exp2f(sB[kt][1]);
          float p2 = exp2f(sB[kt][2]), p3 = exp2f(sB[kt][3]);
          lB += (p0 + p1) + (p2 + p3);
          bf16 tb[4] = {__float2bfloat16(p0), __float2bfloat16(p1),
                        __float2bfloat16(p2), __float2bfloat16(p3)};
          *(ushort4*)(pwB + (l16 << 6) + sl) = *(const ushort4*)tb;
        }
        if constexpr (BOTH) {
          float p0 = exp2f(sA[kt][0]), p1 = exp2f(sA[kt][1]);
          float p2 = exp2f(sA[kt][2]), p3 = exp2f(sA[kt][3]);
          lA += (p0 + p1) + (p2 + p3);
          bf16 ta[4] = {__float2bfloat16(p0), __float2bfloat16(p1),
                        __float2bfloat16(p2), __float2bfloat16(p3)};
          *(ushort4*)(pwA + (l16 << 6) + sl) = *(const ushort4*)ta;
        }
      }
#pragma unroll
      for (int kcl = 0; kcl < 2; ++kcl) {
        int pp = ((kcl << 2) + quad) ^ sw;
        short8 pfB = *(const short8*)(pwB + (l16 << 6) + (pp << 3));
        short8 pfA;
        if constexpr (BOTH) pfA = *(const short8*)(pwA + (l16 << 6) + (pp << 3));
        int kcg = (hh << 1) + kcl;
#pragma unroll
        for (int nd = 0; nd < 8; ++nd) {
          int vrow = (nd << 4) + l16;
          int g = (kcg << 2) + quad;
          int pos = (g & 8) | ((g & 7) ^ (vrow & 7));
          short8 vf = *(const short8*)(lv + vrow * 128 + pos * 8);
          oB[nd] = mfma16(pfB, vf, oB[nd]);
          if constexpr (BOTH) oA[nd] = mfma16(pfA, vf, oA[nd]);
        }
      }
    }
  };

  for (int j = 0; j < nkB; ++j) {
    const int k0 = j << 7;
    // stage K tile [128][128]: chunk c -> row c>>4, pos c&15; low-3 XOR swizzle
#pragma unroll
    for (int i = 0; i < 8; ++i) {
      int c = i * 256 + tid;
      int row = c >> 4, pos = c & 15;
      int g = (pos & 8) | ((pos & 7) ^ (row & 7));
      gload16(Kp + (long)(k0 + row) * 128 + g * 8, lk + (i * 256 + (w << 6)) * 8);
    }
    // stage V tile [128 d][128 k]
#pragma unroll
    for (int i = 0; i < 8; ++i) {
      int c = i * 256 + tid;
      int row = c >> 4, pos = c & 15;
      int g = (pos & 8) | ((pos & 7) ^ (row & 7));
      gload16(Vp + (long)row * 2048 + k0 + g * 8, lv + (i * 256 + (w << 6)) * 8);
    }
    __syncthreads();
    if (j < nkA)
      tile(std::integral_constant<bool, true>{}, k0, j == jmA, j == jmB);
    else
      tile(std::integral_constant<bool, false>{}, k0, false, j == jmB);
    __syncthreads();
  }

  // l: sum quads (lanes sharing l16), invert, redistribute to (quad,rr) rows
  lA += __shfl_xor(lA, 16, 64); lA += __shfl_xor(lA, 32, 64);
  lB += __shfl_xor(lB, 16, 64); lB += __shfl_xor(lB, 32, 64);
  float liA = 1.0f / lA, liB = 1.0f / lB;
  float rlA[4], rlB[4];
#pragma unroll
  for (int rr = 0; rr < 4; ++rr) {
    int src = (quad << 2) + rr;
    rlA[rr] = __shfl(liA, src, 64);
    rlB[rr] = __shfl(liB, src, 64);
  }

  bf16* OpA = O + ((long)(b << 11) + qa0 + (w << 4)) * 2048 + (h << 7);
  bf16* OpB = O + ((long)(b << 11) + qb0 + (w << 4)) * 2048 + (h << 7);
#pragma unroll
  for (int nd = 0; nd < 8; ++nd)
#pragma unroll
    for (int rr = 0; rr < 4; ++rr) {
      int row = (quad << 2) + rr;
      int col = (nd << 4) + l16;
      OpA[(long)row * 2048 + col] = __float2bfloat16(oA[nd][rr] * rlA[rr]);
      OpB[(long)row * 2048 + col] = __float2bfloat16(oB[nd][rr] * rlB[rr]);
    }
}

extern "C" void kernel_launch(void* const* d_in, const int* in_sizes, int n_in,
                              void* d_out, int out_size, void* d_ws, size_t ws_size,
                              hipStream_t stream) {
  (void)in_sizes; (void)n_in; (void)out_size; (void)ws_size;
  const float* x  = (const float*)d_in[0];
  const float* Wq = (const float*)d_in[1];
  const float* Wk = (const float*)d_in[2];
  const float* Wv = (const float*)d_in[3];
  const float* Wo = (const float*)d_in[4];
  char* ws = (char*)d_ws;
  // ws layout (bytes): xb 16.7M | wqkv 12.6M | wo_b 8.4M | qkv 25.2M | Q 16.8M | K 4.2M | Vt 4.2M
  bf16* xb   = (bf16*)(ws);                 // also reused as Ob after gemm1
  bf16* wqkv = (bf16*)(ws + 16777216);
  bf16* wo_b = (bf16*)(ws + 29360128);
  bf16* qkv  = (bf16*)(ws + 37748736);
  bf16* Qr   = (bf16*)(ws + 62914560);
  bf16* Kr   = (bf16*)(ws + 79691776);
  bf16* Vt   = (bf16*)(ws + 83886080);
  bf16* Ob   = xb;  // x dead after QKV GEMM
  float* out = (float*)d_out;

  cast_all_k<<<18432, 256, 0, stream>>>(x, Wq, Wk, Wv, Wo, xb, wqkv, wo_b);

  gemm_bt<bf16><<<dim3(32, 24), 256, 0, stream>>>(xb, wqkv, qkv, 4096, 3072, 2048);
  rope_k<<<20480, 256, 0, stream>>>(qkv, Qr, Kr);
  vtrans_k<<<dim3(64, 4, 8), dim3(32, 8), 0, stream>>>(qkv, Vt);
  attn_k<<<dim3(16, 32), 256, 0, stream>>>(Qr, Kr, Vt, Ob);
  gemm_bt<float><<<dim3(32, 16), 256, 0, stream>>>(Ob, wo_b, out, 4096, 2048, 2048);
}

// Round 5
// 294.663 us; speedup vs baseline: 1.3318x; 1.0563x over previous
//
#include <hip/hip_runtime.h>
#include <hip/hip_bf16.h>

using bf16 = __hip_bfloat16;
typedef __attribute__((ext_vector_type(8))) short short8;   // 8 x bf16 MFMA operand
typedef __attribute__((ext_vector_type(4))) float floatx4;  // MFMA accumulator

#define AS1 __attribute__((address_space(1)))
#define AS3 __attribute__((address_space(3)))

__device__ __forceinline__ floatx4 mfma16(short8 a, short8 b, floatx4 c) {
  return __builtin_amdgcn_mfma_f32_16x16x32_bf16(a, b, c, 0, 0, 0);
}
// async global->LDS, 16B per lane; LDS dest = wave-uniform base + lane*16
__device__ __forceinline__ void gload16(const bf16* g, bf16* l) {
  __builtin_amdgcn_global_load_lds((const AS1 unsigned*)g, (AS3 unsigned*)l, 16, 0, 0);
}

// ------------- fused fp32 -> bf16 casts for all 5 inputs (one launch) -------
__global__ void cast_all_k(const float* __restrict__ x, const float* __restrict__ Wq,
                           const float* __restrict__ Wk, const float* __restrict__ Wv,
                           const float* __restrict__ Wo, bf16* __restrict__ xb,
                           bf16* __restrict__ wqkv, bf16* __restrict__ wo_b) {
  int blk = blockIdx.x;
  const float* src;
  bf16* dst;
  int off;
  if (blk < 8192)       { src = x;  dst = xb;                 off = blk; }
  else if (blk < 12288) { src = Wq; dst = wqkv;               off = blk - 8192; }
  else if (blk < 13312) { src = Wk; dst = wqkv + 2048 * 2048; off = blk - 12288; }
  else if (blk < 14336) { src = Wv; dst = wqkv + 2560 * 2048; off = blk - 13312; }
  else                  { src = Wo; dst = wo_b;               off = blk - 14336; }
  int i = (off * 256 + threadIdx.x) * 4;
  float4 v = *(const float4*)(src + i);
  bf16 t[4] = {__float2bfloat16(v.x), __float2bfloat16(v.y),
               __float2bfloat16(v.z), __float2bfloat16(v.w)};
  *(ushort4*)(dst + i) = *(const ushort4*)t;
}

// ------- GEMM C[M,N] = A[M,K] * B[N,K]^T, bf16 in, OutT out -------
template <typename OutT>
__global__ __launch_bounds__(256, 2)
void gemm_bt(const bf16* __restrict__ A, const bf16* __restrict__ B,
             OutT* __restrict__ C, int M, int N, int K) {
  __shared__ alignas(16) bf16 As[128 * 32];
  __shared__ alignas(16) bf16 Bs[128 * 32];
  const int tid = threadIdx.x;
  const int w = tid >> 6, lane = tid & 63, l16 = lane & 15, quad = lane >> 4;
  const int bm = blockIdx.x << 7, bn = blockIdx.y << 7;
  const int wm = (w & 1) << 6, wn = (w >> 1) << 6;

  const int r = tid >> 2, p = tid & 3;
  const int g0 = (p ^ ((r >> 1) & 3)) << 3;            // source group (elems)
  const int g1 = (p ^ (((r + 64) >> 1) & 3)) << 3;
  const bf16* Ag0 = A + (long)(bm + r) * K + g0;
  const bf16* Ag1 = A + (long)(bm + r + 64) * K + g1;
  const bf16* Bg0 = B + (long)(bn + r) * K + g0;
  const bf16* Bg1 = B + (long)(bn + r + 64) * K + g1;
  bf16* Asw = As + (w << 9);  // wave LDS base (64 lanes * 8 elems)
  bf16* Bsw = Bs + (w << 9);

  floatx4 acc[4][4];
#pragma unroll
  for (int i = 0; i < 4; ++i)
#pragma unroll
    for (int j = 0; j < 4; ++j) acc[i][j] = (floatx4)(0.0f);

  for (int k0 = 0; k0 < K; k0 += 32) {
    gload16(Ag0 + k0, Asw);
    gload16(Ag1 + k0, Asw + 2048);
    gload16(Bg0 + k0, Bsw);
    gload16(Bg1 + k0, Bsw + 2048);
    __syncthreads();
    short8 af[4], bfv[4];
#pragma unroll
    for (int mi = 0; mi < 4; ++mi) {
      int row = wm + (mi << 4) + l16;
      int pos = quad ^ ((row >> 1) & 3);
      af[mi] = *(const short8*)(As + row * 32 + pos * 8);
    }
#pragma unroll
    for (int ni = 0; ni < 4; ++ni) {
      int row = wn + (ni << 4) + l16;
      int pos = quad ^ ((row >> 1) & 3);
      bfv[ni] = *(const short8*)(Bs + row * 32 + pos * 8);
    }
#pragma unroll
    for (int mi = 0; mi < 4; ++mi)
#pragma unroll
      for (int ni = 0; ni < 4; ++ni)
        acc[mi][ni] = mfma16(af[mi], bfv[ni], acc[mi][ni]);
    __syncthreads();
  }

#pragma unroll
  for (int mi = 0; mi < 4; ++mi)
#pragma unroll
    for (int ni = 0; ni < 4; ++ni)
#pragma unroll
      for (int rr = 0; rr < 4; ++rr) {
        int row = bm + wm + (mi << 4) + (quad << 2) + rr;  // C/D: row=quad*4+reg
        int col = bn + wn + (ni << 4) + l16;               //      col=lane&15
        float v = acc[mi][ni][rr];
        if constexpr (sizeof(OutT) == 2)
          C[(long)row * N + col] = __float2bfloat16(v);
        else
          C[(long)row * N + col] = v;
      }
}

// ---------------- RoPE: qkv[4096][3072] -> Q[B,H,S,DH]*scale, K[B,KVH,S,DH] ----
// Q scale = 1/sqrt(128) * log2(e): attention exp(s) becomes exp2(s') directly.
__global__ void rope_k(const bf16* __restrict__ qkv, bf16* __restrict__ Q,
                       bf16* __restrict__ Kd) {
  int idx = blockIdx.x * 256 + threadIdx.x;  // 4096*20*64 threads, d-pair each
  int d = idx & 63;
  int rest = idx >> 6;
  int head = rest % 20;
  int token = rest / 20;
  int s = token & 2047;
  int b = token >> 11;
  const float C0 = 0.20762050593046439f;  // log2(10000)/64
  float i1 = (float)(d >> 1);
  float inv1 = exp2f(-i1 * C0);
  float inv2 = exp2f(-(i1 + 32.0f) * C0);
  float a1 = (float)s * inv1, a2 = (float)s * inv2;
  float s1, c1, s2, c2;
  __sincosf(a1, &s1, &c1);
  __sincosf(a2, &s2, &c2);
  if (head < 16) {
    const bf16* p = qkv + (long)token * 3072 + head * 128 + d;
    float xlo = __bfloat162float(p[0]), xhi = __bfloat162float(p[64]);
    const float sc = 0.08838834764831845f * 1.4426950408889634f;  // 1/sqrt(128)*log2e
    float olo = (xlo * c1 - xhi * s1) * sc;
    float ohi = (xhi * c2 + xlo * s2) * sc;
    bf16* q = Q + ((long)((b << 4) + head) * 2048 + s) * 128 + d;
    q[0] = __float2bfloat16(olo);
    q[64] = __float2bfloat16(ohi);
  } else {
    int kvh = head - 16;
    const bf16* p = qkv + (long)token * 3072 + 2048 + kvh * 128 + d;
    float xlo = __bfloat162float(p[0]), xhi = __bfloat162float(p[64]);
    float olo = xlo * c1 - xhi * s1;
    float ohi = xhi * c2 + xlo * s2;
    bf16* kk = Kd + ((long)((b << 2) + kvh) * 2048 + s) * 128 + d;
    kk[0] = __float2bfloat16(olo);
    kk[64] = __float2bfloat16(ohi);
  }
}

// ---------------- V transpose: qkv V cols -> Vt[B,KVH,DH,S] ----------------
__global__ void vtrans_k(const bf16* __restrict__ qkv, bf16* __restrict__ Vt) {
  __shared__ bf16 t[32][33];
  int x = threadIdx.x, y = threadIdx.y;
  int s0 = blockIdx.x << 5, d0 = blockIdx.y << 5, bkv = blockIdx.z;
  int b = bkv >> 2, kvh = bkv & 3;
  const bf16* src = qkv + (long)((b << 11) + s0) * 3072 + 2560 + kvh * 128 + d0;
#pragma unroll
  for (int yy = y; yy < 32; yy += 8) t[yy][x] = src[(long)yy * 3072 + x];
  __syncthreads();
  bf16* dst = Vt + (long)((bkv << 7) + d0) * 2048 + s0;
#pragma unroll
  for (int yy = y; yy < 32; yy += 8) dst[(long)yy * 2048 + x] = t[x][yy];
}

// -------- flash attention: paired q-tiles, BKV=64, DOUBLE-BUFFERED staging --
// mask: key k valid iff k <= q + 128. Block bx: q-tiles A=bx (light), B=31-bx
// (heavy); 64-key tiles: nkA=bx+3, nkB=min(34-bx,32) -> total 35..37, uniform.
// Straddle masks at jmA=bx+2, jmB=33-bx. Prefetch tile j+1 into buf[(j+1)&1]
// while computing tile j from buf[j&1]; the compiler's vmcnt(0)-before-barrier
// drain lands AFTER the compute phase, so the transfer is hidden.
// QK^T computed transposed (A=K, B=Q): per-lane P = 4 consecutive keys of one
// query -> packed b64 P-store; l is one scalar/lane, reduced once at the end.
__global__ __launch_bounds__(256, 2)
void attn_k(const bf16* __restrict__ Q, const bf16* __restrict__ K,
            const bf16* __restrict__ V, bf16* __restrict__ O) {
  __shared__ alignas(16) bf16 lk[2][64 * 128];  // [key][d]   16KB x2
  __shared__ alignas(16) bf16 lv[2][128 * 64];  // [d][key]   16KB x2
  __shared__ alignas(16) bf16 lpA[4 * 16 * 64]; // P per wave  8KB
  __shared__ alignas(16) bf16 lpB[4 * 16 * 64]; // P per wave  8KB
  const int tid = threadIdx.x, w = tid >> 6, lane = tid & 63;
  const int l16 = lane & 15, quad = lane >> 4;
  const int bx = blockIdx.x;
  const int qa0 = bx << 6, qb0 = (31 - bx) << 6;
  const int nkA = bx + 3;                      // <= 18
  int nkBt = 34 - bx;
  const int nkB = nkBt < 32 ? nkBt : 32;       // clip at S/64
  const int jmA = bx + 2, jmB = 33 - bx;       // straddle tiles
  const int bh = blockIdx.y, b = bh >> 4, h = bh & 15, kvh = h >> 2;
  const bf16* Qp = Q + (long)bh * 2048 * 128;
  const bf16* Kp = K + (long)((b << 2) + kvh) * 2048 * 128;
  const bf16* Vp = V + (long)((b << 2) + kvh) * 128 * 2048;

  short8 qfA[4], qfB[4];  // Q B-frags: n=l16(query), k=quad*8.., kc over DH/32
#pragma unroll
  for (int kc = 0; kc < 4; ++kc) {
    qfA[kc] = *(const short8*)(Qp + (long)(qa0 + (w << 4) + l16) * 128 + kc * 32 + quad * 8);
    qfB[kc] = *(const short8*)(Qp + (long)(qb0 + (w << 4) + l16) * 128 + kc * 32 + quad * 8);
  }

  floatx4 oA[8], oB[8];
#pragma unroll
  for (int i = 0; i < 8; ++i) { oA[i] = (floatx4)(0.0f); oB[i] = (floatx4)(0.0f); }
  float lA = 0.0f, lB = 0.0f;   // per-lane l for query l16 (summed over quads)

  bf16* pwA = lpA + (w << 10);  // 16 q x 64 k per wave
  bf16* pwB = lpB + (w << 10);
  const int sw = l16 & 7;       // P swizzle

  // stage 64-key K/V tile j into buffer bufi (8 gload16 per thread)
  auto stage = [&](int j, int bufi) {
    const int k0 = j << 6;
    bf16* lkb = &lk[bufi][0];
    bf16* lvb = &lv[bufi][0];
#pragma unroll
    for (int i = 0; i < 4; ++i) {  // K [64][128]
      int c = i * 256 + tid;
      int row = c >> 4, pos = c & 15;
      int grp = (pos & 8) | ((pos & 7) ^ (row & 7));
      gload16(Kp + (long)(k0 + row) * 128 + grp * 8, lkb + (i * 256 + (w << 6)) * 8);
    }
#pragma unroll
    for (int i = 0; i < 4; ++i) {  // V [128 d][64 k]
      int c = i * 256 + tid;
      int row = c >> 3, grp = (c & 7) ^ (row & 7);
      gload16(Vp + (long)row * 2048 + k0 + grp * 8, lvb + (i * 256 + (w << 6)) * 8);
    }
  };

  auto tile = [&](auto bothc, int k0, bool maskA, bool maskB, int bufi) {
    constexpr bool BOTH = decltype(bothc)::value;
    const bf16* lkb = &lk[bufi][0];
    const bf16* lvb = &lv[bufi][0];
    floatx4 sA[4], sB[4];
#pragma unroll
    for (int kt = 0; kt < 4; ++kt) {
      sB[kt] = (floatx4)(0.0f);
      if constexpr (BOTH) sA[kt] = (floatx4)(0.0f);
    }
    // S^T = K*Q^T: shared kf (A-operand, m=key) feeds both query tiles
#pragma unroll
    for (int kc = 0; kc < 4; ++kc) {
#pragma unroll
      for (int kt = 0; kt < 4; ++kt) {
        int row = (kt << 4) + l16;
        int g = (kc << 2) + quad;
        int pos = (g & 8) | ((g & 7) ^ (row & 7));
        short8 kf = *(const short8*)(lkb + row * 128 + pos * 8);
        sB[kt] = mfma16(kf, qfB[kc], sB[kt]);
        if constexpr (BOTH) sA[kt] = mfma16(kf, qfA[kc], sA[kt]);
      }
    }
    // mask: S^T value (kt,rr): key = k0+kt*16+quad*4+rr, query = qX0+w*16+l16
    if (maskB) {
      int qg = qb0 + (w << 4) + l16 + 128;
#pragma unroll
      for (int kt = 0; kt < 4; ++kt)
#pragma unroll
        for (int rr = 0; rr < 4; ++rr) {
          int kg = k0 + (kt << 4) + (quad << 2) + rr;
          if (kg > qg) sB[kt][rr] = -1e30f;
        }
    }
    if constexpr (BOTH) {
      if (maskA) {
        int qg = qa0 + (w << 4) + l16 + 128;
#pragma unroll
        for (int kt = 0; kt < 4; ++kt)
#pragma unroll
          for (int rr = 0; rr < 4; ++rr) {
            int kg = k0 + (kt << 4) + (quad << 2) + rr;
            if (kg > qg) sA[kt][rr] = -1e30f;
          }
      }
    }
    // exp2 + packed b64 P-store
#pragma unroll
    for (int t = 0; t < 4; ++t) {
      int slot = (t << 2) + quad;
      int sl = ((((slot >> 1) ^ sw) << 1) | (quad & 1)) << 2;  // elem offset
      {
        float p0 = exp2f(sB[t][0]), p1 = exp2f(sB[t][1]);
        float p2 = exp2f(sB[t][2]), p3 = exp2f(sB[t][3]);
        lB += (p0 + p1) + (p2 + p3);
        bf16 tb[4] = {__float2bfloat16(p0), __float2bfloat16(p1),
                      __float2bfloat16(p2), __float2bfloat16(p3)};
        *(ushort4*)(pwB + (l16 << 6) + sl) = *(const ushort4*)tb;
      }
      if constexpr (BOTH) {
        float p0 = exp2f(sA[t][0]), p1 = exp2f(sA[t][1]);
        float p2 = exp2f(sA[t][2]), p3 = exp2f(sA[t][3]);
        lA += (p0 + p1) + (p2 + p3);
        bf16 ta[4] = {__float2bfloat16(p0), __float2bfloat16(p1),
                      __float2bfloat16(p2), __float2bfloat16(p3)};
        *(ushort4*)(pwA + (l16 << 6) + sl) = *(const ushort4*)ta;
      }
    }
    // PV: shared vf feeds both
#pragma unroll
    for (int kcl = 0; kcl < 2; ++kcl) {
      int pp = ((kcl << 2) + quad) ^ sw;
      short8 pfB = *(const short8*)(pwB + (l16 << 6) + (pp << 3));
      short8 pfA;
      if constexpr (BOTH) pfA = *(const short8*)(pwA + (l16 << 6) + (pp << 3));
      int g = (kcl << 2) + quad;
#pragma unroll
      for (int nd = 0; nd < 8; ++nd) {
        int vrow = (nd << 4) + l16;
        int vpos = g ^ (vrow & 7);
        short8 vf = *(const short8*)(lvb + vrow * 64 + (vpos << 3));
        oB[nd] = mfma16(pfB, vf, oB[nd]);
        if constexpr (BOTH) oA[nd] = mfma16(pfA, vf, oA[nd]);
      }
    }
  };

  stage(0, 0);
  __syncthreads();  // vmcnt(0) drain -> buf0 ready
  for (int j = 0; j < nkB; ++j) {
    if (j + 1 < nkB) stage(j + 1, (j + 1) & 1);  // prefetch overlaps compute
    const int k0 = j << 6;
    if (j < nkA)
      tile(std::integral_constant<bool, true>{}, k0, j == jmA, j == jmB, j & 1);
    else
      tile(std::integral_constant<bool, false>{}, k0, false, j == jmB, j & 1);
    __syncthreads();  // drains prefetch (had full compute phase in flight)
  }

  // l: sum quads (lanes sharing l16), invert, redistribute to (quad,rr) rows
  lA += __shfl_xor(lA, 16, 64); lA += __shfl_xor(lA, 32, 64);
  lB += __shfl_xor(lB, 16, 64); lB += __shfl_xor(lB, 32, 64);
  float liA = 1.0f / lA, liB = 1.0f / lB;
  float rlA[4], rlB[4];
#pragma unroll
  for (int rr = 0; rr < 4; ++rr) {
    int src = (quad << 2) + rr;
    rlA[rr] = __shfl(liA, src, 64);
    rlB[rr] = __shfl(liB, src, 64);
  }

  bf16* OpA = O + ((long)(b << 11) + qa0 + (w << 4)) * 2048 + (h << 7);
  bf16* OpB = O + ((long)(b << 11) + qb0 + (w << 4)) * 2048 + (h << 7);
#pragma unroll
  for (int nd = 0; nd < 8; ++nd)
#pragma unroll
    for (int rr = 0; rr < 4; ++rr) {
      int row = (quad << 2) + rr;
      int col = (nd << 4) + l16;
      OpA[(long)row * 2048 + col] = __float2bfloat16(oA[nd][rr] * rlA[rr]);
      OpB[(long)row * 2048 + col] = __float2bfloat16(oB[nd][rr] * rlB[rr]);
    }
}

extern "C" void kernel_launch(void* const* d_in, const int* in_sizes, int n_in,
                              void* d_out, int out_size, void* d_ws, size_t ws_size,
                              hipStream_t stream) {
  (void)in_sizes; (void)n_in; (void)out_size; (void)ws_size;
  const float* x  = (const float*)d_in[0];
  const float* Wq = (const float*)d_in[1];
  const float* Wk = (const float*)d_in[2];
  const float* Wv = (const float*)d_in[3];
  const float* Wo = (const float*)d_in[4];
  char* ws = (char*)d_ws;
  // ws layout (bytes): xb 16.7M | wqkv 12.6M | wo_b 8.4M | qkv 25.2M | Q 16.8M | K 4.2M | Vt 4.2M
  bf16* xb   = (bf16*)(ws);                 // also reused as Ob after gemm1
  bf16* wqkv = (bf16*)(ws + 16777216);
  bf16* wo_b = (bf16*)(ws + 29360128);
  bf16* qkv  = (bf16*)(ws + 37748736);
  bf16* Qr   = (bf16*)(ws + 62914560);
  bf16* Kr   = (bf16*)(ws + 79691776);
  bf16* Vt   = (bf16*)(ws + 83886080);
  bf16* Ob   = xb;  // x dead after QKV GEMM
  float* out = (float*)d_out;

  cast_all_k<<<18432, 256, 0, stream>>>(x, Wq, Wk, Wv, Wo, xb, wqkv, wo_b);

  gemm_bt<bf16><<<dim3(32, 24), 256, 0, stream>>>(xb, wqkv, qkv, 4096, 3072, 2048);
  rope_k<<<20480, 256, 0, stream>>>(qkv, Qr, Kr);
  vtrans_k<<<dim3(64, 4, 8), dim3(32, 8), 0, stream>>>(qkv, Vt);
  attn_k<<<dim3(16, 32), 256, 0, stream>>>(Qr, Kr, Vt, Ob);
  gemm_bt<float><<<dim3(32, 16), 256, 0, stream>>>(Ob, wo_b, out, 4096, 2048, 2048);
}